// Round 10
// baseline (326.592 us; speedup 1.0000x reference)
//
#include <hip/hip_runtime.h>
#include <hip/hip_bf16.h>
#include <math.h>

typedef __attribute__((ext_vector_type(8))) short s8v;
typedef __attribute__((ext_vector_type(8))) _Float16 h8v;
typedef __attribute__((ext_vector_type(4))) float f4v;
typedef __hip_bfloat16 bf16;

#define NEGF (-3.40282346638528859812e+38f)
#define QSMEM 20480  // f16x2 single-buffer: 4 mats x 64 rows x 40 shorts x 2B
#define BSMEM 20480  // bf16 double-buffer: 2 bufs x 2 mats x 64 x 40 shorts x 2B

enum { EPI_F32 = 0, EPI_BIAS, EPI_BRELU_BF16, EPI_BF16, EPI_FINAL, EPI_T2V, EPI_F16 };

__device__ __forceinline__ float wred_sum(float v) {
#pragma unroll
  for (int m = 1; m < 64; m <<= 1) v += __shfl_xor(v, m, 64);
  return v;
}

// ---------------------------------------------------------------------------
// bf16 MFMA GEMM body, 64x64 tile, double-buffered, stride-40 LDS rows,
// 2-deep register prefetch (alternating reg sets). [R16 proven base]
// EPI_T2V (R21): v-part tiles write vvb (f16 head-major) + vinb (bf16+v_pos)
// straight from the accumulator. EPI_F16 (R22): f16 output for co.
// ---------------------------------------------------------------------------
template <int EPI>
__device__ __forceinline__ void bgemm_body(char* smem, int bx, int by, int bz,
    const bf16* __restrict__ A, const bf16* __restrict__ B, void* __restrict__ C,
    int K, int ldC, long sA, long sB, long sC,
    const float* __restrict__ bias, const void* __restrict__ aux,
    const float* __restrict__ vpos, _Float16* __restrict__ vvb, bf16* __restrict__ vinb) {
  short (*Ahs)[2560] = (short(*)[2560])smem;
  short (*Bhs)[2560] = (short(*)[2560])(smem + 2 * 2560 * 2);
  const short* ah = (const short*)A + (long)bz * sA;
  const short* bh = (const short*)B + (long)bz * sB;
  int tid = threadIdx.x;
  int wv_ = tid >> 6, lane = tid & 63;
  int lrow = tid >> 2, lcol = (tid & 3) << 3;
  int lidx = lrow * 40 + lcol;
  long abase = (long)(bx * 64 + lrow) * K + lcol;
  long bbase = (long)(by * 64 + lrow) * K + lcol;
  int frow = lane & 15, fk = (lane >> 4) << 3;
  int aoff = (wv_ * 16 + frow) * 40 + fk;
  f4v acc[4] = {};
  {
    s8v avh = *(const s8v*)&ah[abase];
    s8v bvh = *(const s8v*)&bh[bbase];
    *(s8v*)&Ahs[0][lidx] = avh;
    *(s8v*)&Bhs[0][lidx] = bvh;
  }
  __syncthreads();
  int nit = K >> 5, buf = 0;
  s8v rAa, rAb, rBa, rBb;
  if (nit > 1) {
    rAa = *(const s8v*)&ah[abase + 32];
    rAb = *(const s8v*)&bh[bbase + 32];
  }
#define B_DSMFMA                                                       \
  {                                                                    \
    s8v afh = *(const s8v*)&Ahs[buf][aoff];                            \
    _Pragma("unroll") for (int nt = 0; nt < 4; nt++) {                 \
      s8v bfh = *(const s8v*)&Bhs[buf][(nt * 16 + frow) * 40 + fk];    \
      acc[nt] = __builtin_amdgcn_mfma_f32_16x16x32_bf16(afh, bfh, acc[nt], 0, 0, 0); \
    }                                                                  \
  }
  for (int it = 0; it < nit; it += 2) {
    if (it + 2 < nit) {
      long ko = (long)(it + 2) << 5;
      rBa = *(const s8v*)&ah[abase + ko];
      rBb = *(const s8v*)&bh[bbase + ko];
    }
    B_DSMFMA
    if (it + 1 < nit) {
      *(s8v*)&Ahs[buf ^ 1][lidx] = rAa;
      *(s8v*)&Bhs[buf ^ 1][lidx] = rAb;
      __syncthreads();
      buf ^= 1;
      if (it + 3 < nit) {
        long ko = (long)(it + 3) << 5;
        rAa = *(const s8v*)&ah[abase + ko];
        rAb = *(const s8v*)&bh[bbase + ko];
      }
      B_DSMFMA
      if (it + 2 < nit) {
        *(s8v*)&Ahs[buf ^ 1][lidx] = rBa;
        *(s8v*)&Bhs[buf ^ 1][lidx] = rBb;
        __syncthreads();
        buf ^= 1;
      }
    }
  }
#undef B_DSMFMA
  int rb = bx * 64 + wv_ * 16 + ((lane >> 4) << 2);
#pragma unroll
  for (int nt = 0; nt < 4; nt++) {
    int gn = by * 64 + nt * 16 + (lane & 15);
#pragma unroll
    for (int rg = 0; rg < 4; rg++) {
      int gm = rb + rg;
      float v = acc[nt][rg];
      long ci = (long)bz * sC + (long)gm * ldC + gn;
      if (EPI == EPI_F32) ((float*)C)[ci] = v;
      else if (EPI == EPI_F16) ((_Float16*)C)[ci] = (_Float16)v;
      else if (EPI == EPI_BIAS) ((float*)C)[ci] = v + bias[gn];
      else if (EPI == EPI_BRELU_BF16) ((bf16*)C)[ci] = __float2bfloat16(fmaxf(v + bias[gn], 0.f));
      else if (EPI == EPI_BF16) ((bf16*)C)[ci] = __float2bfloat16(v);
      else if (EPI == EPI_FINAL)
        ((float*)C)[ci] = v + bias[gm] + ((const float*)aux)[(long)gn * 512 + gm];
      else if (EPI == EPI_T2V) {
        float vb = v + bias[gn];
        int hh = gn >> 6, dd = gn & 63;
        vvb[((long)hh * 4096 + gm) * 64 + dd] = (_Float16)vb;
        vinb[(((long)hh * 256 + (gm >> 4)) * 16 + (gm & 15)) * 64 + dd] =
            __float2bfloat16(vb + vpos[(hh * 16 + (gm & 15)) * 64 + dd]);
      }
    }
  }
}

// ---------------------------------------------------------------------------
// f16x2 split-GEMM machinery: a*b reconstructed from hi/lo f16 planes (lo
// pre-scaled 2^12). THREE MFMAs per fragment pair (ll term dropped, <=2^-22
// per product ~= the f32 reference's own rounding — validated through
// selection in R18/19/21). Single LDS buffer (A+B, 20.5 KB), 2-deep register
// prefetch, 2 barriers/iter, 64-row tiles. Stride-40 rows: <=2-way alias.
// ---------------------------------------------------------------------------

#define HX_DECL                                                     \
  short* L = (short*)smem;                                          \
  const int MS = 64 * 40;                                           \
  int tid = threadIdx.x;                                            \
  int wv = tid >> 6, lane = tid & 63;                               \
  int lrow = tid >> 2, lcol = (tid & 3) << 3;                       \
  int frow = lane & 15, fk = (lane >> 4) << 3;                      \
  int aoff = (wv * 16 + frow) * 40 + fk;                            \
  int soff = lrow * 40 + lcol;                                      \
  f4v acc0[4] = {}, accx[4] = {};

#define HX_STAGE0                                                   \
  {                                                                 \
    *(h8v*)&L[0 * MS + soff] = *(const h8v*)&Ah[abase];             \
    *(h8v*)&L[1 * MS + soff] = *(const h8v*)&Al[abase];             \
    *(h8v*)&L[2 * MS + soff] = *(const h8v*)&Bh[bbase];             \
    *(h8v*)&L[3 * MS + soff] = *(const h8v*)&Bl[bbase];             \
  }                                                                 \
  __syncthreads();

#define HX_DSMFMA                                                   \
  {                                                                 \
    h8v ah = *(const h8v*)&L[aoff];                                 \
    h8v al = *(const h8v*)&L[MS + aoff];                            \
    _Pragma("unroll") for (int nt = 0; nt < 4; nt++) {              \
      int bo = 2 * MS + (nt * 16 + frow) * 40 + fk;                 \
      h8v bh = *(const h8v*)&L[bo];                                 \
      h8v bl = *(const h8v*)&L[bo + MS];                            \
      acc0[nt] = __builtin_amdgcn_mfma_f32_16x16x32_f16(ah, bh, acc0[nt], 0, 0, 0); \
      accx[nt] = __builtin_amdgcn_mfma_f32_16x16x32_f16(ah, bl, accx[nt], 0, 0, 0); \
      accx[nt] = __builtin_amdgcn_mfma_f32_16x16x32_f16(al, bh, accx[nt], 0, 0, 0); \
    }                                                               \
  }

#define HX_LOOP(NIT)                                                \
  h8v rAa, rAb, rAc, rAd, rBa, rBb, rBc, rBd;                       \
  if ((NIT) > 1) {                                                  \
    rAa = *(const h8v*)&Ah[abase + 32];                             \
    rAb = *(const h8v*)&Al[abase + 32];                             \
    rAc = *(const h8v*)&Bh[bbase + 32];                             \
    rAd = *(const h8v*)&Bl[bbase + 32];                             \
  }                                                                 \
  for (int it = 0; it < (NIT); it += 2) {                           \
    if (it + 2 < (NIT)) {                                           \
      long ko = (long)(it + 2) << 5;                                \
      rBa = *(const h8v*)&Ah[abase + ko];                           \
      rBb = *(const h8v*)&Al[abase + ko];                           \
      rBc = *(const h8v*)&Bh[bbase + ko];                           \
      rBd = *(const h8v*)&Bl[bbase + ko];                           \
    }                                                               \
    HX_DSMFMA                                                       \
    if (it + 1 < (NIT)) {                                           \
      __syncthreads();                                              \
      *(h8v*)&L[soff] = rAa;                                        \
      *(h8v*)&L[MS + soff] = rAb;                                   \
      *(h8v*)&L[2 * MS + soff] = rAc;                               \
      *(h8v*)&L[3 * MS + soff] = rAd;                               \
      __syncthreads();                                              \
      if (it + 3 < (NIT)) {                                         \
        long ko = (long)(it + 3) << 5;                              \
        rAa = *(const h8v*)&Ah[abase + ko];                         \
        rAb = *(const h8v*)&Al[abase + ko];                         \
        rAc = *(const h8v*)&Bh[bbase + ko];                         \
        rAd = *(const h8v*)&Bl[bbase + ko];                         \
      }                                                             \
      HX_DSMFMA                                                     \
      if (it + 2 < (NIT)) {                                         \
        __syncthreads();                                            \
        *(h8v*)&L[soff] = rBa;                                      \
        *(h8v*)&L[MS + soff] = rBb;                                 \
        *(h8v*)&L[2 * MS + soff] = rBc;                             \
        *(h8v*)&L[3 * MS + soff] = rBd;                             \
      __syncthreads();                                              \
      }                                                             \
    }                                                               \
  }

#define HX_COMBINE(nt, rg) (acc0[nt][rg] + accx[nt][rg] * (1.f / 4096.f))

// qk projection body with fused RoPE/repack epilogue (table-driven sin/cos).
// R22: rq/rk stored f16 (consumed only by fineslide's f32-reduce softmax).
// D layout (16x16x32 family): col=lane&15, row=(lane>>4)*4+rg.
__device__ __forceinline__ void qk_f16_body(char* smem, int bx, int by,
    const _Float16* __restrict__ Ah, const _Float16* __restrict__ Al,
    const _Float16* __restrict__ Bh, const _Float16* __restrict__ Bl,
    _Float16* __restrict__ qhh, _Float16* __restrict__ qhl,
    _Float16* __restrict__ kinh, _Float16* __restrict__ kinl,
    _Float16* __restrict__ rq, _Float16* __restrict__ rk, const float* __restrict__ kpos,
    const float2* __restrict__ ropet) {
  HX_DECL
  long abase = (long)(bx * 64 + lrow) * 512 + lcol;
  long bbase = (long)(by * 64 + lrow) * 512 + lcol;
  HX_STAGE0
  HX_LOOP(16)
  bool isq = by < 8;
  int h = by & 7;
  int rb = wv * 16 + ((lane >> 4) << 2);
#pragma unroll
  for (int nt = 0; nt < 4; nt++) {
    int dloc = nt * 16 + frow;
    int d2 = dloc >> 1;
#pragma unroll
    for (int rg = 0; rg < 4; rg++) {
      int n = bx * 64 + rb + rg;
      float vf = HX_COMBINE(nt, rg);
      float2 cs = ropet[(long)n * 32 + d2];
      float sv = cs.x, cv = cs.y;
      float vp = __shfl_xor(vf, 1, 64);
      float rr = (dloc & 1) ? (vf * cv + vp * sv) : (vf * cv - vp * sv);
      long oi = ((long)h * 4096 + n) * 64 + dloc;
      if (isq) {
        _Float16 hi = (_Float16)vf;
        qhh[oi] = hi;
        qhl[oi] = (_Float16)((vf - (float)hi) * 4096.f);
        rq[oi] = (_Float16)rr;
      } else {
        rk[oi] = (_Float16)rr;
        float kv = vf + kpos[(h * 16 + (n & 15)) * 64 + dloc];
        _Float16 khi = (_Float16)kv;
        long ki = (((long)h * 256 + (n >> 4)) * 16 + (n & 15)) * 64 + dloc;
        kinh[ki] = khi;
        kinl[ki] = (_Float16)((kv - (float)khi) * 4096.f);
      }
    }
  }
}

// conv: xs = xt @ win^T + b_in, f32 out.
__device__ __forceinline__ void hx_conv_body(char* smem, int bx, int by,
    const _Float16* __restrict__ Ah, const _Float16* __restrict__ Al,
    const _Float16* __restrict__ Bh, const _Float16* __restrict__ Bl,
    float* __restrict__ C, const float* __restrict__ bias) {
  HX_DECL
  long abase = (long)(bx * 64 + lrow) * 512 + lcol;
  long bbase = (long)(by * 64 + lrow) * 512 + lcol;
  HX_STAGE0
  HX_LOOP(16)
  int rb = bx * 64 + wv * 16 + ((lane >> 4) << 2);
#pragma unroll
  for (int nt = 0; nt < 4; nt++) {
    int gn = by * 64 + nt * 16 + frow;
#pragma unroll
    for (int rg = 0; rg < 4; rg++) {
      int gm = rb + rg;
      C[(long)gm * 512 + gn] = HX_COMBINE(nt, rg) + bias[gn];
    }
  }
}

// K-MLP1: hid = relu(kin @ kw1^T + b1), output re-split into hi/lo planes.
__device__ __forceinline__ void hx_mlp1_body(char* smem, int bx, int by,
    const _Float16* __restrict__ Ah, const _Float16* __restrict__ Al,
    const _Float16* __restrict__ Bh, const _Float16* __restrict__ Bl,
    _Float16* __restrict__ Ch, _Float16* __restrict__ Cl, const float* __restrict__ bias) {
  HX_DECL
  long abase = (long)(bx * 64 + lrow) * 1024 + lcol;
  long bbase = (long)(by * 64 + lrow) * 1024 + lcol;
  HX_STAGE0
  HX_LOOP(32)
  int rb = bx * 64 + wv * 16 + ((lane >> 4) << 2);
#pragma unroll
  for (int nt = 0; nt < 4; nt++) {
    int gn = by * 64 + nt * 16 + frow;
#pragma unroll
    for (int rg = 0; rg < 4; rg++) {
      int gm = rb + rg;
      float v = fmaxf(HX_COMBINE(nt, rg) + bias[gn], 0.f);
      _Float16 hi = (_Float16)v;
      long ci = (long)gm * 1024 + gn;
      Ch[ci] = hi;
      Cl[ci] = (_Float16)((v - (float)hi) * 4096.f);
    }
  }
}

// K-MLP2 split-K (16 chunks of KC=64, by = chunk id): f32 partials.
__device__ __forceinline__ void hx_ksplit_body(char* smem, int bx, int by,
    const _Float16* __restrict__ Ah, const _Float16* __restrict__ Al,
    const _Float16* __restrict__ Bh, const _Float16* __restrict__ Bl,
    float* __restrict__ P) {
  HX_DECL
  long kbeg = (long)by << 6;
  long abase = (long)(bx * 64 + lrow) * 1024 + kbeg + lcol;
  long bbase = (long)lrow * 1024 + kbeg + lcol;
  HX_STAGE0
  HX_LOOP(2)
  float* p = P + (long)by * 131072;
  int rb = bx * 64 + wv * 16 + ((lane >> 4) << 2);
#pragma unroll
  for (int nt = 0; nt < 4; nt++) {
    int gn = nt * 16 + frow;
#pragma unroll
    for (int rg = 0; rg < 4; rg++) {
      int gm = rb + rg;
      p[(long)gm * 64 + gn] = HX_COMBINE(nt, rg);
    }
  }
}

// Weight-cast ladder (everything NOT needed by the conv GEMM itself).
__device__ __forceinline__ void prep_elem(long i,
    const float* __restrict__ wq, const float* __restrict__ wk, const float* __restrict__ wv,
    const float* __restrict__ wst, const float* __restrict__ bst,
    const float* __restrict__ kc_w1, const float* __restrict__ kc_w2,
    const float* __restrict__ vc_w1, const float* __restrict__ vc_w2, const float* __restrict__ w_comb,
    const float* __restrict__ w_out, _Float16* __restrict__ wqkh, _Float16* __restrict__ wqkl,
    bf16* __restrict__ wvs, float* __restrict__ bias2,
    _Float16* __restrict__ kw1h, _Float16* __restrict__ kw1l,
    _Float16* __restrict__ kw2h, _Float16* __restrict__ kw2l, bf16* __restrict__ vw1b,
    bf16* __restrict__ vw2b, bf16* __restrict__ wcombb, bf16* __restrict__ woutb) {
  if (i < 524288) {
    int r = (int)(i >> 9), c = (int)(i & 511);
    float w = (r < 512) ? wq[i] : wk[(r - 512) * 512 + c];
    _Float16 hi = (_Float16)w;
    wqkh[i] = hi;
    wqkl[i] = (_Float16)((w - (float)hi) * 4096.f);
    return;
  }
  i -= 524288;
  if (i < 294912) {
    int r = (int)(i >> 9), c = (int)(i & 511);
    float v = 0.f;
    if (r < 512) v = wv[i];
    else if (r < 536) v = wst[(r - 512) * 512 + c];
    wvs[i] = __float2bfloat16(v);
    if (i < 576) bias2[i] = (i >= 512 && i < 536) ? bst[i - 512] : 0.f;
    return;
  }
  i -= 294912;
  if (i < 1048576) {
    float w = kc_w1[i];
    _Float16 hi = (_Float16)w;
    kw1h[i] = hi;
    kw1l[i] = (_Float16)((w - (float)hi) * 4096.f);
    return;
  }
  i -= 1048576;
  if (i < 65536) {
    float w = kc_w2[i];
    _Float16 hi = (_Float16)w;
    kw2h[i] = hi;
    kw2l[i] = (_Float16)((w - (float)hi) * 4096.f);
    return;
  }
  i -= 65536;
  if (i < 1048576) { vw1b[i] = __float2bfloat16(vc_w1[i]); return; }
  i -= 1048576;
  if (i < 65536) { vw2b[i] = __float2bfloat16(vc_w2[i]); return; }
  i -= 65536;
  if (i < 262144) { wcombb[i] = __float2bfloat16(w_comb[i]); return; }
  i -= 262144;
  if (i < 262144) woutb[i] = __float2bfloat16(w_out[i]);
}
#define PREP_TOTAL 3571712l

// ---- standalone kernels ----
template <int EPI>
__global__ __launch_bounds__(256) void gemm_bt(
    const bf16* __restrict__ A, const bf16* __restrict__ B, void* __restrict__ C,
    int K, int ldC, long sA, long sB, long sC,
    const float* __restrict__ bias, const void* __restrict__ aux) {
  __shared__ char smem[BSMEM];
  bgemm_body<EPI>(smem, blockIdx.x, blockIdx.y, blockIdx.z, A, B, C, K, ldC, sA, sB, sC, bias, aux,
                  nullptr, nullptr, nullptr);
}

// conv f16x2 GEMM (y<8) + weight-prep casts (y>=8) in one dispatch.
__global__ __launch_bounds__(256) void k_conv_prep(
    const _Float16* __restrict__ xth, const _Float16* __restrict__ xtl,
    const _Float16* __restrict__ winh, const _Float16* __restrict__ winl,
    float* __restrict__ xsf, const float* __restrict__ b_in,
    const float* __restrict__ wq, const float* __restrict__ wk, const float* __restrict__ wv,
    const float* __restrict__ wst, const float* __restrict__ bst,
    const float* __restrict__ kc_w1, const float* __restrict__ kc_w2,
    const float* __restrict__ vc_w1, const float* __restrict__ vc_w2, const float* __restrict__ w_comb,
    const float* __restrict__ w_out, _Float16* __restrict__ wqkh, _Float16* __restrict__ wqkl,
    bf16* __restrict__ wvs, float* __restrict__ bias2,
    _Float16* __restrict__ kw1h, _Float16* __restrict__ kw1l,
    _Float16* __restrict__ kw2h, _Float16* __restrict__ kw2l, bf16* __restrict__ vw1b,
    bf16* __restrict__ vw2b, bf16* __restrict__ wcombb, bf16* __restrict__ woutb) {
  __shared__ char smem[QSMEM];
  if (blockIdx.y < 8) {
    hx_conv_body(smem, blockIdx.x, blockIdx.y, xth, xtl, winh, winl, xsf, b_in);
  } else {
    long base = (((long)(blockIdx.y - 8) * 64 + blockIdx.x) * 256) + threadIdx.x;
    for (long i = base; i < PREP_TOTAL; i += 16l * 64 * 256)
      prep_elem(i, wq, wk, wv, wst, bst, kc_w1, kc_w2, vc_w1, vc_w2, w_comb, w_out,
                wqkh, wqkl, wvs, bias2, kw1h, kw1l, kw2h, kw2l, vw1b, vw2b, wcombb, woutb);
  }
}

// qk f16x2 split-GEMM (by<16) with FUSED repack epilogue; bf16 T2 GEMM at
// by>=16: v-part tiles (by-16<8) write vvb+vinb directly (EPI_T2V); gate
// tile (by-16==8) writes T2 cols 512..575 (EPI_BIAS).
__global__ __launch_bounds__(256) void k_fused_qk_t2(
    const _Float16* __restrict__ hhi, const _Float16* __restrict__ hlo,
    const _Float16* __restrict__ wqkh, const _Float16* __restrict__ wqkl,
    _Float16* __restrict__ qhh, _Float16* __restrict__ qhl,
    _Float16* __restrict__ kinh, _Float16* __restrict__ kinl,
    _Float16* __restrict__ rq, _Float16* __restrict__ rk, const float* __restrict__ kpos,
    const float2* __restrict__ ropet,
    const bf16* __restrict__ hbf, const bf16* __restrict__ wvs, float* __restrict__ T2,
    const float* __restrict__ bias2, const float* __restrict__ vpos,
    _Float16* __restrict__ vvb, bf16* __restrict__ vinb) {
  __shared__ char smem[QSMEM];
  if (blockIdx.y >= 16) {
    int ty = blockIdx.y - 16;
    if (ty < 8)
      bgemm_body<EPI_T2V>(smem, blockIdx.x, ty, 0, hbf, wvs, T2, 512, 576, 0, 0, 0, bias2, nullptr,
                          vpos, vvb, vinb);
    else
      bgemm_body<EPI_BIAS>(smem, blockIdx.x, ty, 0, hbf, wvs, T2, 512, 576, 0, 0, 0, bias2, nullptr,
                           nullptr, nullptr, nullptr);
    return;
  }
  qk_f16_body(smem, blockIdx.x, blockIdx.y, hhi, hlo, wqkh, wqkl, qhh, qhl, kinh, kinl, rq, rk, kpos,
              ropet);
}

// K-MLP1 f16x2 (y<16) + V-MLP1 bf16 (y>=16).
__global__ __launch_bounds__(256) void k_fused_mlp1(
    const _Float16* __restrict__ kinh, const _Float16* __restrict__ kinl,
    const _Float16* __restrict__ kw1h, const _Float16* __restrict__ kw1l,
    _Float16* __restrict__ hidh, _Float16* __restrict__ hidl, const float* __restrict__ kb1,
    const bf16* __restrict__ vin, const bf16* __restrict__ vw1,
    bf16* __restrict__ hidv, const float* __restrict__ vb1) {
  __shared__ char smem[QSMEM];
  if (blockIdx.y < 16)
    hx_mlp1_body(smem, blockIdx.x, blockIdx.y, kinh, kinl, kw1h, kw1l, hidh, hidl, kb1);
  else
    bgemm_body<EPI_BRELU_BF16>(smem, blockIdx.x, blockIdx.y - 16, 0, vin, vw1, hidv, 1024, 1024, 0, 0, 0,
                               vb1, nullptr, nullptr, nullptr, nullptr);
}

// K-MLP2 f16x2 split-K 16 chunks (y<16) + V-MLP2 bf16 (y==16).
__global__ __launch_bounds__(256) void k_fused_mlp2(
    const _Float16* __restrict__ hidh, const _Float16* __restrict__ hidl,
    const _Float16* __restrict__ kw2h, const _Float16* __restrict__ kw2l, float* __restrict__ kpart,
    const bf16* __restrict__ hidv, const bf16* __restrict__ vw2, float* __restrict__ cvc,
    const float* __restrict__ vb2) {
  __shared__ char smem[QSMEM];
  if (blockIdx.y < 16)
    hx_ksplit_body(smem, blockIdx.x, blockIdx.y, hidh, hidl, kw2h, kw2l, kpart);
  else
    bgemm_body<EPI_BIAS>(smem, blockIdx.x, 0, 0, hidv, vw2, cvc, 1024, 64, 0, 0, 0, vb2, nullptr,
                         nullptr, nullptr, nullptr);
}

// x (512,4096) f32 -> xt (4096,512) f16 hi/lo planes; y==16 slab casts win
// planes + builds the 4096x32 RoPE (sin,cos) table.
__global__ void k_transpose16(const float* __restrict__ x, _Float16* __restrict__ xth,
                              _Float16* __restrict__ xtl,
                              const float* __restrict__ w_in, _Float16* __restrict__ winh,
                              _Float16* __restrict__ winl, float2* __restrict__ ropet) {
  if (blockIdx.y == 16) {
    int tid = threadIdx.y * 32 + threadIdx.x;
    long base = (long)blockIdx.x * 256 + tid;
    for (long i = base; i < 393216; i += 128l * 256) {
      if (i < 262144) {
        float w = w_in[i];
        _Float16 hi = (_Float16)w;
        winh[i] = hi;
        winl[i] = (_Float16)((w - (float)hi) * 4096.f);
      } else {
        int idx = (int)(i - 262144);
        int d2 = idx & 31, n = idx >> 5;
        float inv = exp2f((float)d2 * -0.4152410118609203f);
        float sv, cv;
        sincosf((float)n * inv, &sv, &cv);
        ropet[idx] = make_float2(sv, cv);
      }
    }
    return;
  }
  __shared__ float t[32][33];
  int n0 = blockIdx.x * 32, c0 = blockIdx.y * 32;
  int tx = threadIdx.x, ty = threadIdx.y;
#pragma unroll
  for (int r = ty; r < 32; r += 8) t[r][tx] = x[(long)(c0 + r) * 4096 + n0 + tx];
  __syncthreads();
#pragma unroll
  for (int r = ty; r < 32; r += 8) {
    float v = t[tx][r];
    _Float16 hi = (_Float16)v;
    long o = (long)(n0 + r) * 512 + c0 + tx;
    xth[o] = hi;
    xtl[o] = (_Float16)((v - (float)hi) * 4096.f);
  }
}

// rmsnorm (f64 math on f32 xs) -> h f16 hi/lo planes + bf16 h.
__global__ __launch_bounds__(256) void k_rmsnorm(const float* __restrict__ xs, const float* __restrict__ g,
                                                 _Float16* __restrict__ hhi, _Float16* __restrict__ hlo,
                                                 bf16* __restrict__ hbf) {
  int n = blockIdx.x, t = threadIdx.x;
  const float* row = xs + (long)n * 512;
  double a = (double)row[t], b = (double)row[t + 256];
  double ss = a * a + b * b;
#pragma unroll
  for (int m = 1; m < 64; m <<= 1) ss += __shfl_xor(ss, m, 64);
  __shared__ double red[4];
  if ((t & 63) == 0) red[t >> 6] = ss;
  __syncthreads();
  double tot = red[0] + red[1] + red[2] + red[3];
  double r = 1.0 / sqrt(tot / 512.0 + 1e-6);
  double h0 = a * r * (double)g[t], h1 = b * r * (double)g[t + 256];
  long o = (long)n * 512 + t;
  float f0 = (float)h0, f1 = (float)h1;
  _Float16 a0 = (_Float16)f0, a1 = (_Float16)f1;
  hhi[o] = a0;
  hhi[o + 256] = a1;
  hlo[o] = (_Float16)((f0 - (float)a0) * 4096.f);
  hlo[o + 256] = (_Float16)((f1 - (float)a1) * 4096.f);
  hbf[o] = __float2bfloat16(f0);
  hbf[o + 256] = __float2bfloat16(f1);
}

// split-K f32 partials (16 chunks) + cvc + mem rows -> ckb f16 planes, cvtb.
__global__ void k_repackB(const float* __restrict__ kpart, const float* __restrict__ cvc,
                          const float* __restrict__ mem_k, const float* __restrict__ mem_v,
                          const float* __restrict__ kb2, _Float16* __restrict__ ckbh,
                          _Float16* __restrict__ ckbl, bf16* __restrict__ cvtb) {
  int g = blockIdx.x * 256 + threadIdx.x;
  if (g < 8 * 320 * 64) {
    int d = g & 63, j = (g >> 6) % 320, h = g / (320 * 64);
    float vf = 0.f;
    if (j == 0) vf = mem_k[h * 64 + d];
    else if (j < 257) {
      long ri = ((long)h * 256 + (j - 1)) * 64 + d;
      double s = 0.0;
#pragma unroll
      for (int p = 0; p < 16; p++) s += (double)kpart[(long)p * 131072 + ri];
      vf = (float)(s + (double)kb2[d]);
    }
    _Float16 hi = (_Float16)vf;
    ckbh[g] = hi;
    ckbl[g] = (_Float16)((vf - (float)hi) * 4096.f);
  }
  if (g < 8 * 64 * 288) {
    int j = g % 288, d = (g / 288) & 63, h = g / (288 * 64);
    float v = 0.f;
    if (j == 0) v = mem_v[h * 64 + d];
    else if (j < 257) v = cvc[((long)h * 256 + (j - 1)) * 64 + d];
    cvtb[g] = __float2bfloat16(v);
  }
}

// ---------------------------------------------------------------------------
// FUSED csim+selsm: one block = 16 rows of one head; all rows share
// nv = bx+1 valid cols. MFMA score strip (q/ckb planes direct from global,
// L2-hot, causal skip), staged in LDS, then per-row softmax + exact top-k.
// ---------------------------------------------------------------------------
__global__ __launch_bounds__(256) void k_selsm(
    const _Float16* __restrict__ qhh, const _Float16* __restrict__ qhl,
    const _Float16* __restrict__ ckbh, const _Float16* __restrict__ ckbl,
    bf16* __restrict__ pb, int4* __restrict__ selb) {
  __shared__ float S[16][337];
  int bx = blockIdx.x, h = blockIdx.y;
  int tid = threadIdx.x, wv = tid >> 6, lane = tid & 63;
  int nv = bx + 1;  // valid cols for every row of this tile
  int ntile = (nv + 15) >> 4;
  int frow = lane & 15, fkh = (lane >> 4) << 3;
  long qbase = ((long)h * 4096 + bx * 16 + frow) * 64 + fkh;
  h8v qh0 = *(const h8v*)&qhh[qbase];
  h8v ql0 = *(const h8v*)&qhl[qbase];
  h8v qh1 = *(const h8v*)&qhh[qbase + 32];
  h8v ql1 = *(const h8v*)&qhl[qbase + 32];
  for (int jt = wv; jt < ntile; jt += 4) {
    long bbase = ((long)h * 320 + jt * 16 + frow) * 64 + fkh;
    h8v bh0 = *(const h8v*)&ckbh[bbase];
    h8v bl0 = *(const h8v*)&ckbl[bbase];
    h8v bh1 = *(const h8v*)&ckbh[bbase + 32];
    h8v bl1 = *(const h8v*)&ckbl[bbase + 32];
    f4v a0 = {}, ax = {};
    a0 = __builtin_amdgcn_mfma_f32_16x16x32_f16(qh0, bh0, a0, 0, 0, 0);
    ax = __builtin_amdgcn_mfma_f32_16x16x32_f16(qh0, bl0, ax, 0, 0, 0);
    ax = __builtin_amdgcn_mfma_f32_16x16x32_f16(ql0, bh0, ax, 0, 0, 0);
    a0 = __builtin_amdgcn_mfma_f32_16x16x32_f16(qh1, bh1, a0, 0, 0, 0);
    ax = __builtin_amdgcn_mfma_f32_16x16x32_f16(qh1, bl1, ax, 0, 0, 0);
    ax = __builtin_amdgcn_mfma_f32_16x16x32_f16(ql1, bh1, ax, 0, 0, 0);
#pragma unroll
    for (int rg = 0; rg < 4; rg++)
      S[(lane >> 4) * 4 + rg][jt * 16 + (lane & 15)] =
          (a0[rg] + ax[rg] * (1.f / 4096.f)) * 0.125f;
  }
  __syncthreads();
  // wave wv handles rows wv*4 .. wv*4+3 (full 64-lane wave per row).
  for (int rr = 0; rr < 4; rr++) {
    int lr = wv * 4 + rr;
    int i = bx * 16 + lr;
    long r = (long)h * 4096 + i;
    const float* row = S[lr];
    float s[5], e[5];
    float mx = -INFINITY;
#pragma unroll
    for (int t = 0; t < 5; t++) {
      int j = lane + 64 * t;
      float v = (j < nv) ? row[j] : -INFINITY;
      s[t] = v;
      mx = fmaxf(mx, v);
    }
#pragma unroll
    for (int m = 1; m < 64; m <<= 1) mx = fmaxf(mx, __shfl_xor(mx, m, 64));
    float sum = 0.f;
#pragma unroll
    for (int t = 0; t < 5; t++) {
      int j = lane + 64 * t;
      e[t] = (j < nv) ? __expf(s[t] - mx) : 0.f;
      sum += e[t];
    }
    sum = wred_sum(sum);
    float rinv = 1.f / sum;
    bf16* prow = pb + (long)r * 288;
#pragma unroll
    for (int t = 0; t < 5; t++) {
      int j = lane + 64 * t;
      if (j < 288) prow[j] = __float2bfloat16((j < nv) ? e[t] * rinv : 0.f);
    }
    int nvb = i >> 1;
    int nmv = (nvb + 7) >> 3;
    float vm[4];
    float bestv = -INFINITY;
    int bestm = 0x7fffffff;
#pragma unroll
    for (int t = 0; t < 4; t++) {
      int m = lane + 64 * t;
      float v = -INFINITY;
      if (m < nmv) v = (m + 1 < nv) ? row[m + 1] : NEGF;
      vm[t] = v;
      if (v > bestv) { bestv = v; bestm = m; }
    }
#pragma unroll
    for (int mk = 1; mk < 64; mk <<= 1) {
      float ov = __shfl_xor(bestv, mk, 64);
      int om = __shfl_xor(bestm, mk, 64);
      if (ov > bestv || (ov == bestv && om < bestm)) { bestv = ov; bestm = om; }
    }
    int m0 = bestm;
    int cnt0 = min(8, nvb - 8 * m0);
    float rv = -INFINITY;
    int rm = 0x7fffffff;
#pragma unroll
    for (int t = 0; t < 4; t++) {
      int m = lane + 64 * t;
      if (m != m0 && vm[t] > rv) { rv = vm[t]; rm = m; }
    }
#pragma unroll
    for (int mk = 1; mk < 64; mk <<= 1) {
      float ov = __shfl_xor(rv, mk, 64);
      int om = __shfl_xor(rm, mk, 64);
      if (ov > rv || (ov == rv && om < rm)) { rv = ov; rm = om; }
    }
    float Ml = fmaxf(-1000.f, bestv);
    float z = 0.f;
#pragma unroll
    for (int t = 0; t < 4; t++) {
      int m = lane + 64 * t;
      if (m < nmv) z += (float)min(8, nvb - 8 * m) * expf(vm[t] - Ml);
    }
    z = wred_sum(z) + expf(-1000.f - Ml);
    int fb0 = 0, fb1 = 0, mk0 = 0, mk1 = 0;
    if (nmv > 0) {
      float sv0 = expf(bestv - Ml) / z;
      fb0 = 8 * m0;
      mk0 = sv0 > 1e-10f;
      if (cnt0 >= 2) { fb1 = fb0 + 1; mk1 = mk0; }
      else if (nmv > 1) {
        float sv1 = expf(rv - Ml) / z;
        fb1 = 8 * rm;
        mk1 = sv1 > 1e-10f;
      }
    }
    if (lane == 0) selb[r] = make_int4(fb0, fb1, mk0, mk1);
  }
}

// Per (h,i): fine attention (selected + diag) + sliding window + gated
// combine. R22: rq/rk/vv/co are f16 (f32 math via converts; halves HBM).
__global__ __launch_bounds__(256) void k_fineslide(const _Float16* __restrict__ rq,
                                                   const _Float16* __restrict__ rk,
                                                   const _Float16* __restrict__ vv,
                                                   const _Float16* __restrict__ co,
                                                   const int4* __restrict__ selb, const float* __restrict__ T2,
                                                   bf16* __restrict__ comb) {
  int r = blockIdx.x * 4 + (threadIdx.x >> 6);
  int d = threadIdx.x & 63;
  int h = r >> 12, i = r & 4095;
  long hb = (long)h * 4096 * 64;
  float qd = (float)rq[hb + (long)i * 64 + d];
  int4 s4 = selb[r];
  int dg = i >> 1;
  int tok[6] = {2 * s4.x, 2 * s4.x + 1, 2 * s4.y, 2 * s4.y + 1, 2 * dg, 2 * dg + 1};
  int ok6[6] = {s4.z, s4.z, s4.w, s4.w, 1, (i & 1)};
  float sim[6], val[6];
#pragma unroll
  for (int j = 0; j < 6; j++) {
    float kd = (float)rk[hb + (long)tok[j] * 64 + d];
    val[j] = (float)vv[hb + (long)tok[j] * 64 + d];
    float p = wred_sum(qd * kd);
    sim[j] = ok6[j] ? p * 0.125f : NEGF;
  }
  float mx = sim[0];
#pragma unroll
  for (int j = 1; j < 6; j++) mx = fmaxf(mx, sim[j]);
  float den = 0.f, fo = 0.f;
#pragma unroll
  for (int j = 0; j < 6; j++) {
    float e_ = __expf(sim[j] - mx);
    den += e_;
    fo += e_ * val[j];
  }
  fo /= den;
  float ssim[9], sval[9];
#pragma unroll
  for (int t = 0; t < 9; t++) {
    int tk = i - 8 + t;
    int okt = tk >= 0;
    int tc = okt ? tk : 0;
    float kd = (float)rk[hb + (long)tc * 64 + d];
    sval[t] = okt ? (float)vv[hb + (long)tc * 64 + d] : 0.f;
    float p = wred_sum(qd * kd);
    ssim[t] = okt ? p * 0.125f : NEGF;
  }
  float mx2 = ssim[8];
#pragma unroll
  for (int t = 0; t < 8; t++) mx2 = fmaxf(mx2, ssim[t]);
  float den2 = 0.f, so = 0.f;
#pragma unroll
  for (int t = 0; t < 9; t++) {
    float e_ = __expf(ssim[t] - mx2);
    den2 += e_;
    so += e_ * sval[t];
  }
  so /= den2;
  const float* gb = T2 + (long)i * 576 + 512 + h * 3;
  float g0 = 1.f / (1.f + __expf(-gb[0]));
  float g1 = 1.f / (1.f + __expf(-gb[1]));
  float g2 = 1.f / (1.f + __expf(-gb[2]));
  float cd = (float)co[hb + (long)i * 64 + d];
  comb[(long)i * 512 + h * 64 + d] = __float2bfloat16(g0 * cd + g1 * fo + g2 * so);
}

extern "C" void kernel_launch(void* const* d_in, const int* in_sizes, int n_in, void* d_out, int out_size,
                              void* d_ws, size_t ws_size, hipStream_t stream) {
  (void)in_sizes; (void)n_in; (void)out_size; (void)ws_size;
  const float* x = (const float*)d_in[0];
  const float* w_in = (const float*)d_in[1];
  const float* b_in = (const float*)d_in[2];
  const float* g_norm = (const float*)d_in[3];
  const float* wq = (const float*)d_in[4];
  const float* wk = (const float*)d_in[5];
  const float* wv = (const float*)d_in[6];
  const float* k_pos = (const float*)d_in[7];
  const float* v_pos = (const float*)d_in[8];
  const float* mem_k = (const float*)d_in[9];
  const float* mem_v = (const float*)d_in[10];
  const float* kc_w1 = (const float*)d_in[11];
  const float* kc_b1 = (const float*)d_in[12];
  const float* kc_w2 = (const float*)d_in[13];
  const float* kc_b2 = (const float*)d_in[14];
  const float* vc_w1 = (const float*)d_in[15];
  const float* vc_b1 = (const float*)d_in[16];
  const float* vc_w2 = (const float*)d_in[17];
  const float* vc_b2 = (const float*)d_in[18];
  const float* w_strat = (const float*)d_in[19];
  const float* b_strat = (const float*)d_in[20];
  const float* w_comb = (const float*)d_in[21];
  const float* w_out = (const float*)d_in[22];
  const float* b_out = (const float*)d_in[23];

  char* wsp = (char*)d_ws;
  size_t off = 0;
  auto alloc = [&](size_t b) -> void* {
    void* p = wsp + off;
    off += (b + 255) & ~(size_t)255;
    return p;
  };
  float* xsf = (float*)alloc(4096l * 512 * 4);
  _Float16* hhi = (_Float16*)alloc(4096l * 512 * 2);
  _Float16* hlo = (_Float16*)alloc(4096l * 512 * 2);
  bf16* hbf = (bf16*)alloc(4096l * 512 * 2);
  _Float16* winh = (_Float16*)alloc(512l * 512 * 2);
  _Float16* winl = (_Float16*)alloc(512l * 512 * 2);
  _Float16* wqkh = (_Float16*)alloc(1024l * 512 * 2);
  _Float16* wqkl = (_Float16*)alloc(1024l * 512 * 2);
  bf16* wvs = (bf16*)alloc(576l * 512 * 2);
  float* bias2 = (float*)alloc(576 * 4);
  float2* ropet = (float2*)alloc(4096l * 32 * 8);
  float* T2 = (float*)alloc(4096l * 576 * 4);
  _Float16* qhh = (_Float16*)alloc(8l * 4096 * 64 * 2);
  _Float16* qhl = (_Float16*)alloc(8l * 4096 * 64 * 2);
  _Float16* rq = (_Float16*)alloc(8l * 4096 * 64 * 2);
  _Float16* rk = (_Float16*)alloc(8l * 4096 * 64 * 2);
  _Float16* vvb = (_Float16*)alloc(8l * 4096 * 64 * 2);
  char* xthl = (char*)alloc(2l * 4096 * 512 * 2);  // xt planes, later hid planes
  _Float16* xth = (_Float16*)xthl;
  _Float16* xtl = xth + 4096l * 512;
  _Float16* hidh = xth;  // 2048*1024 == 4096*512 elems per plane
  _Float16* hidl = xtl;
  char* kinpb = (char*)alloc(2048l * 1024 * 8 + 2048l * 1024 * 2);  // kin planes + vin, later pb
  _Float16* kinh = (_Float16*)kinpb;
  _Float16* kinl = kinh + 2048l * 1024;
  bf16* vinb = (bf16*)(kinpb + 2l * 2048 * 1024 * 2);
  bf16* pb = (bf16*)kinpb;
  _Float16* kw1h = (_Float16*)alloc(1024l * 1024 * 2);
  _Float16* kw1l = (_Float16*)alloc(1024l * 1024 * 2);
  _Float16* kw2h = (_Float16*)alloc(64l * 1024 * 2);
  _Float16* kw2l = (_Float16*)alloc(64l * 1024 * 2);
  bf16* vw1b = (bf16*)alloc(1024l * 1024 * 2);
  bf16* vw2b = (bf16*)alloc(64l * 1024 * 2);
  bf16* hidv = (bf16*)alloc(2048l * 1024 * 2);
  float* cvc = (float*)alloc(2048l * 64 * 4);
  _Float16* ckbh = (_Float16*)alloc(8l * 320 * 64 * 2);
  _Float16* ckbl = (_Float16*)alloc(8l * 320 * 64 * 2);
  bf16* cvtb = (bf16*)alloc(8l * 64 * 288 * 2);
  int4* selb = (int4*)alloc(32768l * 16);
  _Float16* co = (_Float16*)alloc(8l * 4096 * 64 * 2);
  bf16* comb = (bf16*)alloc(4096l * 512 * 2);
  bf16* zb = (bf16*)alloc(4096l * 512 * 2);
  bf16* wcombb = (bf16*)alloc(512l * 512 * 2);
  bf16* woutb = (bf16*)alloc(512l * 512 * 2);
  float* kpart = (float*)alloc(16l * 2048 * 64 * 4);  // split-K f32 partials (16 chunks)

  // ---- transpose to f16 planes + conv-weight plane cast + RoPE table ----
  k_transpose16<<<dim3(128, 17), dim3(32, 8), 0, stream>>>(x, xth, xtl, w_in, winh, winl, ropet);
  // ---- conv (f16x2) + all remaining weight prep in one dispatch ----
  k_conv_prep<<<dim3(64, 24), 256, 0, stream>>>(xth, xtl, winh, winl, xsf, b_in, wq, wk, wv, w_strat,
                                                b_strat, kc_w1, kc_w2, vc_w1, vc_w2, w_comb, w_out,
                                                wqkh, wqkl, wvs, bias2, kw1h, kw1l, kw2h, kw2l,
                                                vw1b, vw2b, wcombb, woutb);
  k_rmsnorm<<<4096, 256, 0, stream>>>(xsf, g_norm, hhi, hlo, hbf);
  // ---- qk f16x2 GEMM with fused repack epilogue (+ T2 bf16 GEMM w/ fused
  //      v-repack) ----
  k_fused_qk_t2<<<dim3(64, 25, 1), 256, 0, stream>>>(hhi, hlo, wqkh, wqkl, qhh, qhl, kinh, kinl, rq, rk,
                                                     k_pos, ropet, hbf, wvs, T2, bias2, v_pos, vvb, vinb);
  k_fused_mlp1<<<dim3(32, 32, 1), 256, 0, stream>>>(kinh, kinl, kw1h, kw1l, hidh, hidl, kc_b1, vinb, vw1b,
                                                    hidv, vc_b1);
  k_fused_mlp2<<<dim3(32, 17, 1), 256, 0, stream>>>(hidh, hidl, kw2h, kw2l, kpart, hidv, vw2b, cvc, vc_b2);
  k_repackB<<<640, 256, 0, stream>>>(kpart, cvc, mem_k, mem_v, kc_b2, ckbh, ckbl, cvtb);
  // ---- FUSED csim+softmax+topk ----
  k_selsm<<<dim3(256, 8), 256, 0, stream>>>(qhh, qhl, ckbh, ckbl, pb, selb);
  gemm_bt<EPI_F16><<<dim3(64, 1, 8), 256, 0, stream>>>(pb, cvtb, co, 288, 64, 4096l * 288, 64l * 288,
                                                       4096l * 64, nullptr, nullptr);
  k_fineslide<<<8192, 256, 0, stream>>>(rq, rk, vvb, co, selb, T2, comb);
  // ---- output mixing ----
  gemm_bt<EPI_BF16><<<dim3(64, 8, 1), 256, 0, stream>>>(comb, wcombb, zb, 512, 512, 0, 0, 0, nullptr, nullptr);
  gemm_bt<EPI_FINAL><<<dim3(8, 64, 1), 256, 0, stream>>>(woutb, zb, d_out, 512, 4096, 0, 0, 0, b_out, xsf);
}

// Round 11
// 317.957 us; speedup vs baseline: 1.0272x; 1.0272x over previous
//
#include <hip/hip_runtime.h>
#include <hip/hip_bf16.h>
#include <math.h>

typedef __attribute__((ext_vector_type(8))) short s8v;
typedef __attribute__((ext_vector_type(8))) _Float16 h8v;
typedef __attribute__((ext_vector_type(4))) float f4v;
typedef __hip_bfloat16 bf16;

#define NEGF (-3.40282346638528859812e+38f)
#define QSMEM 20480  // f16x2 single-buffer: 4 mats x 64 rows x 40 shorts x 2B
#define BSMEM 20480  // bf16 double-buffer: 2 bufs x 2 mats x 64 x 40 shorts x 2B

enum { EPI_F32 = 0, EPI_BIAS, EPI_BRELU_BF16, EPI_BF16, EPI_FINAL, EPI_T2V };

__device__ __forceinline__ float wred_sum(float v) {
#pragma unroll
  for (int m = 1; m < 64; m <<= 1) v += __shfl_xor(v, m, 64);
  return v;
}

// ---------------------------------------------------------------------------
// bf16 MFMA GEMM body, 64x64 tile, double-buffered, stride-40 LDS rows,
// 2-deep register prefetch (alternating reg sets). [R16 proven base]
// EPI_T2V (R21): v-part tiles write vvb (f32 head-major) + vinb (bf16+v_pos)
// straight from the accumulator; T2's v columns are never materialized.
// ---------------------------------------------------------------------------
template <int EPI>
__device__ __forceinline__ void bgemm_body(char* smem, int bx, int by, int bz,
    const bf16* __restrict__ A, const bf16* __restrict__ B, void* __restrict__ C,
    int K, int ldC, long sA, long sB, long sC,
    const float* __restrict__ bias, const void* __restrict__ aux,
    const float* __restrict__ vpos, float* __restrict__ vvb, bf16* __restrict__ vinb) {
  short (*Ahs)[2560] = (short(*)[2560])smem;
  short (*Bhs)[2560] = (short(*)[2560])(smem + 2 * 2560 * 2);
  const short* ah = (const short*)A + (long)bz * sA;
  const short* bh = (const short*)B + (long)bz * sB;
  int tid = threadIdx.x;
  int wv_ = tid >> 6, lane = tid & 63;
  int lrow = tid >> 2, lcol = (tid & 3) << 3;
  int lidx = lrow * 40 + lcol;
  long abase = (long)(bx * 64 + lrow) * K + lcol;
  long bbase = (long)(by * 64 + lrow) * K + lcol;
  int frow = lane & 15, fk = (lane >> 4) << 3;
  int aoff = (wv_ * 16 + frow) * 40 + fk;
  f4v acc[4] = {};
  {
    s8v avh = *(const s8v*)&ah[abase];
    s8v bvh = *(const s8v*)&bh[bbase];
    *(s8v*)&Ahs[0][lidx] = avh;
    *(s8v*)&Bhs[0][lidx] = bvh;
  }
  __syncthreads();
  int nit = K >> 5, buf = 0;
  s8v rAa, rAb, rBa, rBb;
  if (nit > 1) {
    rAa = *(const s8v*)&ah[abase + 32];
    rAb = *(const s8v*)&bh[bbase + 32];
  }
#define B_DSMFMA                                                       \
  {                                                                    \
    s8v afh = *(const s8v*)&Ahs[buf][aoff];                            \
    _Pragma("unroll") for (int nt = 0; nt < 4; nt++) {                 \
      s8v bfh = *(const s8v*)&Bhs[buf][(nt * 16 + frow) * 40 + fk];    \
      acc[nt] = __builtin_amdgcn_mfma_f32_16x16x32_bf16(afh, bfh, acc[nt], 0, 0, 0); \
    }                                                                  \
  }
  for (int it = 0; it < nit; it += 2) {
    if (it + 2 < nit) {
      long ko = (long)(it + 2) << 5;
      rBa = *(const s8v*)&ah[abase + ko];
      rBb = *(const s8v*)&bh[bbase + ko];
    }
    B_DSMFMA
    if (it + 1 < nit) {
      *(s8v*)&Ahs[buf ^ 1][lidx] = rAa;
      *(s8v*)&Bhs[buf ^ 1][lidx] = rAb;
      __syncthreads();
      buf ^= 1;
      if (it + 3 < nit) {
        long ko = (long)(it + 3) << 5;
        rAa = *(const s8v*)&ah[abase + ko];
        rAb = *(const s8v*)&bh[bbase + ko];
      }
      B_DSMFMA
      if (it + 2 < nit) {
        *(s8v*)&Ahs[buf ^ 1][lidx] = rBa;
        *(s8v*)&Bhs[buf ^ 1][lidx] = rBb;
        __syncthreads();
        buf ^= 1;
      }
    }
  }
#undef B_DSMFMA
  int rb = bx * 64 + wv_ * 16 + ((lane >> 4) << 2);
#pragma unroll
  for (int nt = 0; nt < 4; nt++) {
    int gn = by * 64 + nt * 16 + (lane & 15);
#pragma unroll
    for (int rg = 0; rg < 4; rg++) {
      int gm = rb + rg;
      float v = acc[nt][rg];
      long ci = (long)bz * sC + (long)gm * ldC + gn;
      if (EPI == EPI_F32) ((float*)C)[ci] = v;
      else if (EPI == EPI_BIAS) ((float*)C)[ci] = v + bias[gn];
      else if (EPI == EPI_BRELU_BF16) ((bf16*)C)[ci] = __float2bfloat16(fmaxf(v + bias[gn], 0.f));
      else if (EPI == EPI_BF16) ((bf16*)C)[ci] = __float2bfloat16(v);
      else if (EPI == EPI_FINAL)
        ((float*)C)[ci] = v + bias[gm] + ((const float*)aux)[(long)gn * 512 + gm];
      else if (EPI == EPI_T2V) {
        float vb = v + bias[gn];
        int hh = gn >> 6, dd = gn & 63;
        vvb[((long)hh * 4096 + gm) * 64 + dd] = vb;
        vinb[(((long)hh * 256 + (gm >> 4)) * 16 + (gm & 15)) * 64 + dd] =
            __float2bfloat16(vb + vpos[(hh * 16 + (gm & 15)) * 64 + dd]);
      }
    }
  }
}

// ---------------------------------------------------------------------------
// f16x2 split-GEMM machinery: a*b reconstructed from hi/lo f16 planes (lo
// pre-scaled 2^12). THREE MFMAs per fragment pair (hh -> acc0, hl+lh ->
// accx @2^-12); the ll term (<=2^-22 per product ~= the f32 reference's own
// rounding) is dropped — validated end-to-end through selection in R18/R19/R21.
// Single LDS buffer (A+B, 20.5 KB), 2-deep register prefetch, 2 barriers/iter,
// 64-row tiles. LDS row stride 40 shorts (80B): 16B-aligned b128, <=2-way alias.
// ---------------------------------------------------------------------------

#define HX_DECL                                                     \
  short* L = (short*)smem;                                          \
  const int MS = 64 * 40;                                           \
  int tid = threadIdx.x;                                            \
  int wv = tid >> 6, lane = tid & 63;                               \
  int lrow = tid >> 2, lcol = (tid & 3) << 3;                       \
  int frow = lane & 15, fk = (lane >> 4) << 3;                      \
  int aoff = (wv * 16 + frow) * 40 + fk;                            \
  int soff = lrow * 40 + lcol;                                      \
  f4v acc0[4] = {}, accx[4] = {};

#define HX_STAGE0                                                   \
  {                                                                 \
    *(h8v*)&L[0 * MS + soff] = *(const h8v*)&Ah[abase];             \
    *(h8v*)&L[1 * MS + soff] = *(const h8v*)&Al[abase];             \
    *(h8v*)&L[2 * MS + soff] = *(const h8v*)&Bh[bbase];             \
    *(h8v*)&L[3 * MS + soff] = *(const h8v*)&Bl[bbase];             \
  }                                                                 \
  __syncthreads();

#define HX_DSMFMA                                                   \
  {                                                                 \
    h8v ah = *(const h8v*)&L[aoff];                                 \
    h8v al = *(const h8v*)&L[MS + aoff];                            \
    _Pragma("unroll") for (int nt = 0; nt < 4; nt++) {              \
      int bo = 2 * MS + (nt * 16 + frow) * 40 + fk;                 \
      h8v bh = *(const h8v*)&L[bo];                                 \
      h8v bl = *(const h8v*)&L[bo + MS];                            \
      acc0[nt] = __builtin_amdgcn_mfma_f32_16x16x32_f16(ah, bh, acc0[nt], 0, 0, 0); \
      accx[nt] = __builtin_amdgcn_mfma_f32_16x16x32_f16(ah, bl, accx[nt], 0, 0, 0); \
      accx[nt] = __builtin_amdgcn_mfma_f32_16x16x32_f16(al, bh, accx[nt], 0, 0, 0); \
    }                                                               \
  }

#define HX_LOOP(NIT)                                                \
  h8v rAa, rAb, rAc, rAd, rBa, rBb, rBc, rBd;                       \
  if ((NIT) > 1) {                                                  \
    rAa = *(const h8v*)&Ah[abase + 32];                             \
    rAb = *(const h8v*)&Al[abase + 32];                             \
    rAc = *(const h8v*)&Bh[bbase + 32];                             \
    rAd = *(const h8v*)&Bl[bbase + 32];                             \
  }                                                                 \
  for (int it = 0; it < (NIT); it += 2) {                           \
    if (it + 2 < (NIT)) {                                           \
      long ko = (long)(it + 2) << 5;                                \
      rBa = *(const h8v*)&Ah[abase + ko];                           \
      rBb = *(const h8v*)&Al[abase + ko];                           \
      rBc = *(const h8v*)&Bh[bbase + ko];                           \
      rBd = *(const h8v*)&Bl[bbase + ko];                           \
    }                                                               \
    HX_DSMFMA                                                       \
    if (it + 1 < (NIT)) {                                           \
      __syncthreads();                                              \
      *(h8v*)&L[soff] = rAa;                                        \
      *(h8v*)&L[MS + soff] = rAb;                                   \
      *(h8v*)&L[2 * MS + soff] = rAc;                               \
      *(h8v*)&L[3 * MS + soff] = rAd;                               \
      __syncthreads();                                              \
      if (it + 3 < (NIT)) {                                         \
        long ko = (long)(it + 3) << 5;                              \
        rAa = *(const h8v*)&Ah[abase + ko];                         \
        rAb = *(const h8v*)&Al[abase + ko];                         \
        rAc = *(const h8v*)&Bh[bbase + ko];                         \
        rAd = *(const h8v*)&Bl[bbase + ko];                         \
      }                                                             \
      HX_DSMFMA                                                     \
      if (it + 2 < (NIT)) {                                         \
        __syncthreads();                                            \
        *(h8v*)&L[soff] = rBa;                                      \
        *(h8v*)&L[MS + soff] = rBb;                                 \
        *(h8v*)&L[2 * MS + soff] = rBc;                             \
        *(h8v*)&L[3 * MS + soff] = rBd;                             \
      __syncthreads();                                              \
      }                                                             \
    }                                                               \
  }

#define HX_COMBINE(nt, rg) (acc0[nt][rg] + accx[nt][rg] * (1.f / 4096.f))

// qk projection body with fused RoPE/repack epilogue (table-driven sin/cos).
// D layout (16x16x32 family): col=lane&15, row=(lane>>4)*4+rg.
__device__ __forceinline__ void qk_f16_body(char* smem, int bx, int by,
    const _Float16* __restrict__ Ah, const _Float16* __restrict__ Al,
    const _Float16* __restrict__ Bh, const _Float16* __restrict__ Bl,
    _Float16* __restrict__ qhh, _Float16* __restrict__ qhl,
    _Float16* __restrict__ kinh, _Float16* __restrict__ kinl,
    float* __restrict__ rq, float* __restrict__ rk, const float* __restrict__ kpos,
    const float2* __restrict__ ropet) {
  HX_DECL
  long abase = (long)(bx * 64 + lrow) * 512 + lcol;
  long bbase = (long)(by * 64 + lrow) * 512 + lcol;
  HX_STAGE0
  HX_LOOP(16)
  bool isq = by < 8;
  int h = by & 7;
  int rb = wv * 16 + ((lane >> 4) << 2);
#pragma unroll
  for (int nt = 0; nt < 4; nt++) {
    int dloc = nt * 16 + frow;
    int d2 = dloc >> 1;
#pragma unroll
    for (int rg = 0; rg < 4; rg++) {
      int n = bx * 64 + rb + rg;
      float vf = HX_COMBINE(nt, rg);
      float2 cs = ropet[(long)n * 32 + d2];
      float sv = cs.x, cv = cs.y;
      float vp = __shfl_xor(vf, 1, 64);
      float rr = (dloc & 1) ? (vf * cv + vp * sv) : (vf * cv - vp * sv);
      long oi = ((long)h * 4096 + n) * 64 + dloc;
      if (isq) {
        _Float16 hi = (_Float16)vf;
        qhh[oi] = hi;
        qhl[oi] = (_Float16)((vf - (float)hi) * 4096.f);
        rq[oi] = rr;
      } else {
        rk[oi] = rr;
        float kv = vf + kpos[(h * 16 + (n & 15)) * 64 + dloc];
        _Float16 khi = (_Float16)kv;
        long ki = (((long)h * 256 + (n >> 4)) * 16 + (n & 15)) * 64 + dloc;
        kinh[ki] = khi;
        kinl[ki] = (_Float16)((kv - (float)khi) * 4096.f);
      }
    }
  }
}

// conv: xs = xt @ win^T + b_in, f32 out.
__device__ __forceinline__ void hx_conv_body(char* smem, int bx, int by,
    const _Float16* __restrict__ Ah, const _Float16* __restrict__ Al,
    const _Float16* __restrict__ Bh, const _Float16* __restrict__ Bl,
    float* __restrict__ C, const float* __restrict__ bias) {
  HX_DECL
  long abase = (long)(bx * 64 + lrow) * 512 + lcol;
  long bbase = (long)(by * 64 + lrow) * 512 + lcol;
  HX_STAGE0
  HX_LOOP(16)
  int rb = bx * 64 + wv * 16 + ((lane >> 4) << 2);
#pragma unroll
  for (int nt = 0; nt < 4; nt++) {
    int gn = by * 64 + nt * 16 + frow;
#pragma unroll
    for (int rg = 0; rg < 4; rg++) {
      int gm = rb + rg;
      C[(long)gm * 512 + gn] = HX_COMBINE(nt, rg) + bias[gn];
    }
  }
}

// K-MLP1: hid = relu(kin @ kw1^T + b1), output re-split into hi/lo planes.
__device__ __forceinline__ void hx_mlp1_body(char* smem, int bx, int by,
    const _Float16* __restrict__ Ah, const _Float16* __restrict__ Al,
    const _Float16* __restrict__ Bh, const _Float16* __restrict__ Bl,
    _Float16* __restrict__ Ch, _Float16* __restrict__ Cl, const float* __restrict__ bias) {
  HX_DECL
  long abase = (long)(bx * 64 + lrow) * 1024 + lcol;
  long bbase = (long)(by * 64 + lrow) * 1024 + lcol;
  HX_STAGE0
  HX_LOOP(32)
  int rb = bx * 64 + wv * 16 + ((lane >> 4) << 2);
#pragma unroll
  for (int nt = 0; nt < 4; nt++) {
    int gn = by * 64 + nt * 16 + frow;
#pragma unroll
    for (int rg = 0; rg < 4; rg++) {
      int gm = rb + rg;
      float v = fmaxf(HX_COMBINE(nt, rg) + bias[gn], 0.f);
      _Float16 hi = (_Float16)v;
      long ci = (long)gm * 1024 + gn;
      Ch[ci] = hi;
      Cl[ci] = (_Float16)((v - (float)hi) * 4096.f);
    }
  }
}

// K-MLP2 split-K (16 chunks of KC=64, by = chunk id): f32 partials.
__device__ __forceinline__ void hx_ksplit_body(char* smem, int bx, int by,
    const _Float16* __restrict__ Ah, const _Float16* __restrict__ Al,
    const _Float16* __restrict__ Bh, const _Float16* __restrict__ Bl,
    float* __restrict__ P) {
  HX_DECL
  long kbeg = (long)by << 6;
  long abase = (long)(bx * 64 + lrow) * 1024 + kbeg + lcol;
  long bbase = (long)lrow * 1024 + kbeg + lcol;
  HX_STAGE0
  HX_LOOP(2)
  float* p = P + (long)by * 131072;
  int rb = bx * 64 + wv * 16 + ((lane >> 4) << 2);
#pragma unroll
  for (int nt = 0; nt < 4; nt++) {
    int gn = nt * 16 + frow;
#pragma unroll
    for (int rg = 0; rg < 4; rg++) {
      int gm = rb + rg;
      p[(long)gm * 64 + gn] = HX_COMBINE(nt, rg);
    }
  }
}

// Weight-cast ladder (everything NOT needed by the conv GEMM itself).
__device__ __forceinline__ void prep_elem(long i,
    const float* __restrict__ wq, const float* __restrict__ wk, const float* __restrict__ wv,
    const float* __restrict__ wst, const float* __restrict__ bst,
    const float* __restrict__ kc_w1, const float* __restrict__ kc_w2,
    const float* __restrict__ vc_w1, const float* __restrict__ vc_w2, const float* __restrict__ w_comb,
    const float* __restrict__ w_out, _Float16* __restrict__ wqkh, _Float16* __restrict__ wqkl,
    bf16* __restrict__ wvs, float* __restrict__ bias2,
    _Float16* __restrict__ kw1h, _Float16* __restrict__ kw1l,
    _Float16* __restrict__ kw2h, _Float16* __restrict__ kw2l, bf16* __restrict__ vw1b,
    bf16* __restrict__ vw2b, bf16* __restrict__ wcombb, bf16* __restrict__ woutb) {
  if (i < 524288) {
    int r = (int)(i >> 9), c = (int)(i & 511);
    float w = (r < 512) ? wq[i] : wk[(r - 512) * 512 + c];
    _Float16 hi = (_Float16)w;
    wqkh[i] = hi;
    wqkl[i] = (_Float16)((w - (float)hi) * 4096.f);
    return;
  }
  i -= 524288;
  if (i < 294912) {
    int r = (int)(i >> 9), c = (int)(i & 511);
    float v = 0.f;
    if (r < 512) v = wv[i];
    else if (r < 536) v = wst[(r - 512) * 512 + c];
    wvs[i] = __float2bfloat16(v);
    if (i < 576) bias2[i] = (i >= 512 && i < 536) ? bst[i - 512] : 0.f;
    return;
  }
  i -= 294912;
  if (i < 1048576) {
    float w = kc_w1[i];
    _Float16 hi = (_Float16)w;
    kw1h[i] = hi;
    kw1l[i] = (_Float16)((w - (float)hi) * 4096.f);
    return;
  }
  i -= 1048576;
  if (i < 65536) {
    float w = kc_w2[i];
    _Float16 hi = (_Float16)w;
    kw2h[i] = hi;
    kw2l[i] = (_Float16)((w - (float)hi) * 4096.f);
    return;
  }
  i -= 65536;
  if (i < 1048576) { vw1b[i] = __float2bfloat16(vc_w1[i]); return; }
  i -= 1048576;
  if (i < 65536) { vw2b[i] = __float2bfloat16(vc_w2[i]); return; }
  i -= 65536;
  if (i < 262144) { wcombb[i] = __float2bfloat16(w_comb[i]); return; }
  i -= 262144;
  if (i < 262144) woutb[i] = __float2bfloat16(w_out[i]);
}
#define PREP_TOTAL 3571712l

// ---- standalone kernels ----
template <int EPI>
__global__ __launch_bounds__(256) void gemm_bt(
    const bf16* __restrict__ A, const bf16* __restrict__ B, void* __restrict__ C,
    int K, int ldC, long sA, long sB, long sC,
    const float* __restrict__ bias, const void* __restrict__ aux) {
  __shared__ char smem[BSMEM];
  bgemm_body<EPI>(smem, blockIdx.x, blockIdx.y, blockIdx.z, A, B, C, K, ldC, sA, sB, sC, bias, aux,
                  nullptr, nullptr, nullptr);
}

// conv f16x2 GEMM (y<8) + weight-prep casts (y>=8) in one dispatch.
__global__ __launch_bounds__(256) void k_conv_prep(
    const _Float16* __restrict__ xth, const _Float16* __restrict__ xtl,
    const _Float16* __restrict__ winh, const _Float16* __restrict__ winl,
    float* __restrict__ xsf, const float* __restrict__ b_in,
    const float* __restrict__ wq, const float* __restrict__ wk, const float* __restrict__ wv,
    const float* __restrict__ wst, const float* __restrict__ bst,
    const float* __restrict__ kc_w1, const float* __restrict__ kc_w2,
    const float* __restrict__ vc_w1, const float* __restrict__ vc_w2, const float* __restrict__ w_comb,
    const float* __restrict__ w_out, _Float16* __restrict__ wqkh, _Float16* __restrict__ wqkl,
    bf16* __restrict__ wvs, float* __restrict__ bias2,
    _Float16* __restrict__ kw1h, _Float16* __restrict__ kw1l,
    _Float16* __restrict__ kw2h, _Float16* __restrict__ kw2l, bf16* __restrict__ vw1b,
    bf16* __restrict__ vw2b, bf16* __restrict__ wcombb, bf16* __restrict__ woutb) {
  __shared__ char smem[QSMEM];
  if (blockIdx.y < 8) {
    hx_conv_body(smem, blockIdx.x, blockIdx.y, xth, xtl, winh, winl, xsf, b_in);
  } else {
    long base = (((long)(blockIdx.y - 8) * 64 + blockIdx.x) * 256) + threadIdx.x;
    for (long i = base; i < PREP_TOTAL; i += 16l * 64 * 256)
      prep_elem(i, wq, wk, wv, wst, bst, kc_w1, kc_w2, vc_w1, vc_w2, w_comb, w_out,
                wqkh, wqkl, wvs, bias2, kw1h, kw1l, kw2h, kw2l, vw1b, vw2b, wcombb, woutb);
  }
}

// qk f16x2 split-GEMM (by<16) with FUSED repack epilogue; bf16 T2 GEMM at
// by>=16: v-part tiles (by-16<8) write vvb+vinb directly (EPI_T2V, replaces
// k_repackV); gate tile (by-16==8) writes T2 cols 512..575 (EPI_BIAS).
__global__ __launch_bounds__(256) void k_fused_qk_t2(
    const _Float16* __restrict__ hhi, const _Float16* __restrict__ hlo,
    const _Float16* __restrict__ wqkh, const _Float16* __restrict__ wqkl,
    _Float16* __restrict__ qhh, _Float16* __restrict__ qhl,
    _Float16* __restrict__ kinh, _Float16* __restrict__ kinl,
    float* __restrict__ rq, float* __restrict__ rk, const float* __restrict__ kpos,
    const float2* __restrict__ ropet,
    const bf16* __restrict__ hbf, const bf16* __restrict__ wvs, float* __restrict__ T2,
    const float* __restrict__ bias2, const float* __restrict__ vpos,
    float* __restrict__ vvb, bf16* __restrict__ vinb) {
  __shared__ char smem[QSMEM];
  if (blockIdx.y >= 16) {
    int ty = blockIdx.y - 16;
    if (ty < 8)
      bgemm_body<EPI_T2V>(smem, blockIdx.x, ty, 0, hbf, wvs, T2, 512, 576, 0, 0, 0, bias2, nullptr,
                          vpos, vvb, vinb);
    else
      bgemm_body<EPI_BIAS>(smem, blockIdx.x, ty, 0, hbf, wvs, T2, 512, 576, 0, 0, 0, bias2, nullptr,
                           nullptr, nullptr, nullptr);
    return;
  }
  qk_f16_body(smem, blockIdx.x, blockIdx.y, hhi, hlo, wqkh, wqkl, qhh, qhl, kinh, kinl, rq, rk, kpos,
              ropet);
}

// K-MLP1 f16x2 (y<16) + V-MLP1 bf16 (y>=16).
__global__ __launch_bounds__(256) void k_fused_mlp1(
    const _Float16* __restrict__ kinh, const _Float16* __restrict__ kinl,
    const _Float16* __restrict__ kw1h, const _Float16* __restrict__ kw1l,
    _Float16* __restrict__ hidh, _Float16* __restrict__ hidl, const float* __restrict__ kb1,
    const bf16* __restrict__ vin, const bf16* __restrict__ vw1,
    bf16* __restrict__ hidv, const float* __restrict__ vb1) {
  __shared__ char smem[QSMEM];
  if (blockIdx.y < 16)
    hx_mlp1_body(smem, blockIdx.x, blockIdx.y, kinh, kinl, kw1h, kw1l, hidh, hidl, kb1);
  else
    bgemm_body<EPI_BRELU_BF16>(smem, blockIdx.x, blockIdx.y - 16, 0, vin, vw1, hidv, 1024, 1024, 0, 0, 0,
                               vb1, nullptr, nullptr, nullptr, nullptr);
}

// K-MLP2 f16x2 split-K 16 chunks (y<16) + V-MLP2 bf16 (y==16).
__global__ __launch_bounds__(256) void k_fused_mlp2(
    const _Float16* __restrict__ hidh, const _Float16* __restrict__ hidl,
    const _Float16* __restrict__ kw2h, const _Float16* __restrict__ kw2l, float* __restrict__ kpart,
    const bf16* __restrict__ hidv, const bf16* __restrict__ vw2, float* __restrict__ cvc,
    const float* __restrict__ vb2) {
  __shared__ char smem[QSMEM];
  if (blockIdx.y < 16)
    hx_ksplit_body(smem, blockIdx.x, blockIdx.y, hidh, hidl, kw2h, kw2l, kpart);
  else
    bgemm_body<EPI_BIAS>(smem, blockIdx.x, 0, 0, hidv, vw2, cvc, 1024, 64, 0, 0, 0, vb2, nullptr,
                         nullptr, nullptr, nullptr);
}

// x (512,4096) f32 -> xt (4096,512) f16 hi/lo planes; y==16 slab casts win
// planes + builds the 4096x32 RoPE (sin,cos) table.
__global__ void k_transpose16(const float* __restrict__ x, _Float16* __restrict__ xth,
                              _Float16* __restrict__ xtl,
                              const float* __restrict__ w_in, _Float16* __restrict__ winh,
                              _Float16* __restrict__ winl, float2* __restrict__ ropet) {
  if (blockIdx.y == 16) {
    int tid = threadIdx.y * 32 + threadIdx.x;
    long base = (long)blockIdx.x * 256 + tid;
    for (long i = base; i < 393216; i += 128l * 256) {
      if (i < 262144) {
        float w = w_in[i];
        _Float16 hi = (_Float16)w;
        winh[i] = hi;
        winl[i] = (_Float16)((w - (float)hi) * 4096.f);
      } else {
        int idx = (int)(i - 262144);
        int d2 = idx & 31, n = idx >> 5;
        float inv = exp2f((float)d2 * -0.4152410118609203f);
        float sv, cv;
        sincosf((float)n * inv, &sv, &cv);
        ropet[idx] = make_float2(sv, cv);
      }
    }
    return;
  }
  __shared__ float t[32][33];
  int n0 = blockIdx.x * 32, c0 = blockIdx.y * 32;
  int tx = threadIdx.x, ty = threadIdx.y;
#pragma unroll
  for (int r = ty; r < 32; r += 8) t[r][tx] = x[(long)(c0 + r) * 4096 + n0 + tx];
  __syncthreads();
#pragma unroll
  for (int r = ty; r < 32; r += 8) {
    float v = t[tx][r];
    _Float16 hi = (_Float16)v;
    long o = (long)(n0 + r) * 512 + c0 + tx;
    xth[o] = hi;
    xtl[o] = (_Float16)((v - (float)hi) * 4096.f);
  }
}

// rmsnorm (f64 math on f32 xs) -> h f16 hi/lo planes + bf16 h.
__global__ __launch_bounds__(256) void k_rmsnorm(const float* __restrict__ xs, const float* __restrict__ g,
                                                 _Float16* __restrict__ hhi, _Float16* __restrict__ hlo,
                                                 bf16* __restrict__ hbf) {
  int n = blockIdx.x, t = threadIdx.x;
  const float* row = xs + (long)n * 512;
  double a = (double)row[t], b = (double)row[t + 256];
  double ss = a * a + b * b;
#pragma unroll
  for (int m = 1; m < 64; m <<= 1) ss += __shfl_xor(ss, m, 64);
  __shared__ double red[4];
  if ((t & 63) == 0) red[t >> 6] = ss;
  __syncthreads();
  double tot = red[0] + red[1] + red[2] + red[3];
  double r = 1.0 / sqrt(tot / 512.0 + 1e-6);
  double h0 = a * r * (double)g[t], h1 = b * r * (double)g[t + 256];
  long o = (long)n * 512 + t;
  float f0 = (float)h0, f1 = (float)h1;
  _Float16 a0 = (_Float16)f0, a1 = (_Float16)f1;
  hhi[o] = a0;
  hhi[o + 256] = a1;
  hlo[o] = (_Float16)((f0 - (float)a0) * 4096.f);
  hlo[o + 256] = (_Float16)((f1 - (float)a1) * 4096.f);
  hbf[o] = __float2bfloat16(f0);
  hbf[o + 256] = __float2bfloat16(f1);
}

// split-K f32 partials (16 chunks) + cvc + mem rows -> ckb f16 planes, cvtb.
__global__ void k_repackB(const float* __restrict__ kpart, const float* __restrict__ cvc,
                          const float* __restrict__ mem_k, const float* __restrict__ mem_v,
                          const float* __restrict__ kb2, _Float16* __restrict__ ckbh,
                          _Float16* __restrict__ ckbl, bf16* __restrict__ cvtb) {
  int g = blockIdx.x * 256 + threadIdx.x;
  if (g < 8 * 320 * 64) {
    int d = g & 63, j = (g >> 6) % 320, h = g / (320 * 64);
    float vf = 0.f;
    if (j == 0) vf = mem_k[h * 64 + d];
    else if (j < 257) {
      long ri = ((long)h * 256 + (j - 1)) * 64 + d;
      double s = 0.0;
#pragma unroll
      for (int p = 0; p < 16; p++) s += (double)kpart[(long)p * 131072 + ri];
      vf = (float)(s + (double)kb2[d]);
    }
    _Float16 hi = (_Float16)vf;
    ckbh[g] = hi;
    ckbl[g] = (_Float16)((vf - (float)hi) * 4096.f);
  }
  if (g < 8 * 64 * 288) {
    int j = g % 288, d = (g / 288) & 63, h = g / (288 * 64);
    float v = 0.f;
    if (j == 0) v = mem_v[h * 64 + d];
    else if (j < 257) v = cvc[((long)h * 256 + (j - 1)) * 64 + d];
    cvtb[g] = __float2bfloat16(v);
  }
}

// ---------------------------------------------------------------------------
// FUSED csim+selsm: one block = 16 rows of one head; all rows share
// nv = bx+1 valid cols. MFMA score strip (q/ckb planes direct from global,
// L2-hot, causal skip), staged in LDS, then per-row softmax + exact top-k.
// ---------------------------------------------------------------------------
__global__ __launch_bounds__(256) void k_selsm(
    const _Float16* __restrict__ qhh, const _Float16* __restrict__ qhl,
    const _Float16* __restrict__ ckbh, const _Float16* __restrict__ ckbl,
    bf16* __restrict__ pb, int4* __restrict__ selb) {
  __shared__ float S[16][337];
  int bx = blockIdx.x, h = blockIdx.y;
  int tid = threadIdx.x, wv = tid >> 6, lane = tid & 63;
  int nv = bx + 1;  // valid cols for every row of this tile
  int ntile = (nv + 15) >> 4;
  int frow = lane & 15, fkh = (lane >> 4) << 3;
  long qbase = ((long)h * 4096 + bx * 16 + frow) * 64 + fkh;
  h8v qh0 = *(const h8v*)&qhh[qbase];
  h8v ql0 = *(const h8v*)&qhl[qbase];
  h8v qh1 = *(const h8v*)&qhh[qbase + 32];
  h8v ql1 = *(const h8v*)&qhl[qbase + 32];
  for (int jt = wv; jt < ntile; jt += 4) {
    long bbase = ((long)h * 320 + jt * 16 + frow) * 64 + fkh;
    h8v bh0 = *(const h8v*)&ckbh[bbase];
    h8v bl0 = *(const h8v*)&ckbl[bbase];
    h8v bh1 = *(const h8v*)&ckbh[bbase + 32];
    h8v bl1 = *(const h8v*)&ckbl[bbase + 32];
    f4v a0 = {}, ax = {};
    a0 = __builtin_amdgcn_mfma_f32_16x16x32_f16(qh0, bh0, a0, 0, 0, 0);
    ax = __builtin_amdgcn_mfma_f32_16x16x32_f16(qh0, bl0, ax, 0, 0, 0);
    ax = __builtin_amdgcn_mfma_f32_16x16x32_f16(ql0, bh0, ax, 0, 0, 0);
    a0 = __builtin_amdgcn_mfma_f32_16x16x32_f16(qh1, bh1, a0, 0, 0, 0);
    ax = __builtin_amdgcn_mfma_f32_16x16x32_f16(qh1, bl1, ax, 0, 0, 0);
    ax = __builtin_amdgcn_mfma_f32_16x16x32_f16(ql1, bh1, ax, 0, 0, 0);
#pragma unroll
    for (int rg = 0; rg < 4; rg++)
      S[(lane >> 4) * 4 + rg][jt * 16 + (lane & 15)] =
          (a0[rg] + ax[rg] * (1.f / 4096.f)) * 0.125f;
  }
  __syncthreads();
  // wave wv handles rows wv*4 .. wv*4+3 (full 64-lane wave per row).
  for (int rr = 0; rr < 4; rr++) {
    int lr = wv * 4 + rr;
    int i = bx * 16 + lr;
    long r = (long)h * 4096 + i;
    const float* row = S[lr];
    float s[5], e[5];
    float mx = -INFINITY;
#pragma unroll
    for (int t = 0; t < 5; t++) {
      int j = lane + 64 * t;
      float v = (j < nv) ? row[j] : -INFINITY;
      s[t] = v;
      mx = fmaxf(mx, v);
    }
#pragma unroll
    for (int m = 1; m < 64; m <<= 1) mx = fmaxf(mx, __shfl_xor(mx, m, 64));
    float sum = 0.f;
#pragma unroll
    for (int t = 0; t < 5; t++) {
      int j = lane + 64 * t;
      e[t] = (j < nv) ? __expf(s[t] - mx) : 0.f;
      sum += e[t];
    }
    sum = wred_sum(sum);
    float rinv = 1.f / sum;
    bf16* prow = pb + (long)r * 288;
#pragma unroll
    for (int t = 0; t < 5; t++) {
      int j = lane + 64 * t;
      if (j < 288) prow[j] = __float2bfloat16((j < nv) ? e[t] * rinv : 0.f);
    }
    int nvb = i >> 1;
    int nmv = (nvb + 7) >> 3;
    float vm[4];
    float bestv = -INFINITY;
    int bestm = 0x7fffffff;
#pragma unroll
    for (int t = 0; t < 4; t++) {
      int m = lane + 64 * t;
      float v = -INFINITY;
      if (m < nmv) v = (m + 1 < nv) ? row[m + 1] : NEGF;
      vm[t] = v;
      if (v > bestv) { bestv = v; bestm = m; }
    }
#pragma unroll
    for (int mk = 1; mk < 64; mk <<= 1) {
      float ov = __shfl_xor(bestv, mk, 64);
      int om = __shfl_xor(bestm, mk, 64);
      if (ov > bestv || (ov == bestv && om < bestm)) { bestv = ov; bestm = om; }
    }
    int m0 = bestm;
    int cnt0 = min(8, nvb - 8 * m0);
    float rv = -INFINITY;
    int rm = 0x7fffffff;
#pragma unroll
    for (int t = 0; t < 4; t++) {
      int m = lane + 64 * t;
      if (m != m0 && vm[t] > rv) { rv = vm[t]; rm = m; }
    }
#pragma unroll
    for (int mk = 1; mk < 64; mk <<= 1) {
      float ov = __shfl_xor(rv, mk, 64);
      int om = __shfl_xor(rm, mk, 64);
      if (ov > rv || (ov == rv && om < rm)) { rv = ov; rm = om; }
    }
    float Ml = fmaxf(-1000.f, bestv);
    float z = 0.f;
#pragma unroll
    for (int t = 0; t < 4; t++) {
      int m = lane + 64 * t;
      if (m < nmv) z += (float)min(8, nvb - 8 * m) * expf(vm[t] - Ml);
    }
    z = wred_sum(z) + expf(-1000.f - Ml);
    int fb0 = 0, fb1 = 0, mk0 = 0, mk1 = 0;
    if (nmv > 0) {
      float sv0 = expf(bestv - Ml) / z;
      fb0 = 8 * m0;
      mk0 = sv0 > 1e-10f;
      if (cnt0 >= 2) { fb1 = fb0 + 1; mk1 = mk0; }
      else if (nmv > 1) {
        float sv1 = expf(rv - Ml) / z;
        fb1 = 8 * rm;
        mk1 = sv1 > 1e-10f;
      }
    }
    if (lane == 0) selb[r] = make_int4(fb0, fb1, mk0, mk1);
  }
}

// Per (h,i): fine attention (selected + diag) + sliding window + gated combine.
__global__ __launch_bounds__(256) void k_fineslide(const float* __restrict__ rq, const float* __restrict__ rk,
                                                   const float* __restrict__ vv, const float* __restrict__ co,
                                                   const int4* __restrict__ selb, const float* __restrict__ T2,
                                                   bf16* __restrict__ comb) {
  int r = blockIdx.x * 4 + (threadIdx.x >> 6);
  int d = threadIdx.x & 63;
  int h = r >> 12, i = r & 4095;
  long hb = (long)h * 4096 * 64;
  float qd = rq[hb + (long)i * 64 + d];
  int4 s4 = selb[r];
  int dg = i >> 1;
  int tok[6] = {2 * s4.x, 2 * s4.x + 1, 2 * s4.y, 2 * s4.y + 1, 2 * dg, 2 * dg + 1};
  int ok6[6] = {s4.z, s4.z, s4.w, s4.w, 1, (i & 1)};
  float sim[6], val[6];
#pragma unroll
  for (int j = 0; j < 6; j++) {
    float kd = rk[hb + (long)tok[j] * 64 + d];
    val[j] = vv[hb + (long)tok[j] * 64 + d];
    float p = wred_sum(qd * kd);
    sim[j] = ok6[j] ? p * 0.125f : NEGF;
  }
  float mx = sim[0];
#pragma unroll
  for (int j = 1; j < 6; j++) mx = fmaxf(mx, sim[j]);
  float den = 0.f, fo = 0.f;
#pragma unroll
  for (int j = 0; j < 6; j++) {
    float e_ = __expf(sim[j] - mx);
    den += e_;
    fo += e_ * val[j];
  }
  fo /= den;
  float ssim[9], sval[9];
#pragma unroll
  for (int t = 0; t < 9; t++) {
    int tk = i - 8 + t;
    int okt = tk >= 0;
    int tc = okt ? tk : 0;
    float kd = rk[hb + (long)tc * 64 + d];
    sval[t] = okt ? vv[hb + (long)tc * 64 + d] : 0.f;
    float p = wred_sum(qd * kd);
    ssim[t] = okt ? p * 0.125f : NEGF;
  }
  float mx2 = ssim[8];
#pragma unroll
  for (int t = 0; t < 8; t++) mx2 = fmaxf(mx2, ssim[t]);
  float den2 = 0.f, so = 0.f;
#pragma unroll
  for (int t = 0; t < 9; t++) {
    float e_ = __expf(ssim[t] - mx2);
    den2 += e_;
    so += e_ * sval[t];
  }
  so /= den2;
  const float* gb = T2 + (long)i * 576 + 512 + h * 3;
  float g0 = 1.f / (1.f + __expf(-gb[0]));
  float g1 = 1.f / (1.f + __expf(-gb[1]));
  float g2 = 1.f / (1.f + __expf(-gb[2]));
  float cd = co[hb + (long)i * 64 + d];
  comb[(long)i * 512 + h * 64 + d] = __float2bfloat16(g0 * cd + g1 * fo + g2 * so);
}

extern "C" void kernel_launch(void* const* d_in, const int* in_sizes, int n_in, void* d_out, int out_size,
                              void* d_ws, size_t ws_size, hipStream_t stream) {
  (void)in_sizes; (void)n_in; (void)out_size; (void)ws_size;
  const float* x = (const float*)d_in[0];
  const float* w_in = (const float*)d_in[1];
  const float* b_in = (const float*)d_in[2];
  const float* g_norm = (const float*)d_in[3];
  const float* wq = (const float*)d_in[4];
  const float* wk = (const float*)d_in[5];
  const float* wv = (const float*)d_in[6];
  const float* k_pos = (const float*)d_in[7];
  const float* v_pos = (const float*)d_in[8];
  const float* mem_k = (const float*)d_in[9];
  const float* mem_v = (const float*)d_in[10];
  const float* kc_w1 = (const float*)d_in[11];
  const float* kc_b1 = (const float*)d_in[12];
  const float* kc_w2 = (const float*)d_in[13];
  const float* kc_b2 = (const float*)d_in[14];
  const float* vc_w1 = (const float*)d_in[15];
  const float* vc_b1 = (const float*)d_in[16];
  const float* vc_w2 = (const float*)d_in[17];
  const float* vc_b2 = (const float*)d_in[18];
  const float* w_strat = (const float*)d_in[19];
  const float* b_strat = (const float*)d_in[20];
  const float* w_comb = (const float*)d_in[21];
  const float* w_out = (const float*)d_in[22];
  const float* b_out = (const float*)d_in[23];

  char* wsp = (char*)d_ws;
  size_t off = 0;
  auto alloc = [&](size_t b) -> void* {
    void* p = wsp + off;
    off += (b + 255) & ~(size_t)255;
    return p;
  };
  float* xsf = (float*)alloc(4096l * 512 * 4);
  _Float16* hhi = (_Float16*)alloc(4096l * 512 * 2);
  _Float16* hlo = (_Float16*)alloc(4096l * 512 * 2);
  bf16* hbf = (bf16*)alloc(4096l * 512 * 2);
  _Float16* winh = (_Float16*)alloc(512l * 512 * 2);
  _Float16* winl = (_Float16*)alloc(512l * 512 * 2);
  _Float16* wqkh = (_Float16*)alloc(1024l * 512 * 2);
  _Float16* wqkl = (_Float16*)alloc(1024l * 512 * 2);
  bf16* wvs = (bf16*)alloc(576l * 512 * 2);
  float* bias2 = (float*)alloc(576 * 4);
  float2* ropet = (float2*)alloc(4096l * 32 * 8);
  float* T2 = (float*)alloc(4096l * 576 * 4);
  _Float16* qhh = (_Float16*)alloc(8l * 4096 * 64 * 2);
  _Float16* qhl = (_Float16*)alloc(8l * 4096 * 64 * 2);
  float* rq = (float*)alloc(8l * 4096 * 64 * 4);
  float* rk = (float*)alloc(8l * 4096 * 64 * 4);
  float* vvb = (float*)alloc(8l * 4096 * 64 * 4);
  char* xthl = (char*)alloc(2l * 4096 * 512 * 2);  // xt planes, later hid planes
  _Float16* xth = (_Float16*)xthl;
  _Float16* xtl = xth + 4096l * 512;
  _Float16* hidh = xth;  // 2048*1024 == 4096*512 elems per plane
  _Float16* hidl = xtl;
  char* kinpb = (char*)alloc(2048l * 1024 * 8 + 2048l * 1024 * 2);  // kin planes + vin, later pb
  _Float16* kinh = (_Float16*)kinpb;
  _Float16* kinl = kinh + 2048l * 1024;
  bf16* vinb = (bf16*)(kinpb + 2l * 2048 * 1024 * 2);
  bf16* pb = (bf16*)kinpb;
  _Float16* kw1h = (_Float16*)alloc(1024l * 1024 * 2);
  _Float16* kw1l = (_Float16*)alloc(1024l * 1024 * 2);
  _Float16* kw2h = (_Float16*)alloc(64l * 1024 * 2);
  _Float16* kw2l = (_Float16*)alloc(64l * 1024 * 2);
  bf16* vw1b = (bf16*)alloc(1024l * 1024 * 2);
  bf16* vw2b = (bf16*)alloc(64l * 1024 * 2);
  bf16* hidv = (bf16*)alloc(2048l * 1024 * 2);
  float* cvc = (float*)alloc(2048l * 64 * 4);
  _Float16* ckbh = (_Float16*)alloc(8l * 320 * 64 * 2);
  _Float16* ckbl = (_Float16*)alloc(8l * 320 * 64 * 2);
  bf16* cvtb = (bf16*)alloc(8l * 64 * 288 * 2);
  int4* selb = (int4*)alloc(32768l * 16);
  float* co = (float*)alloc(8l * 4096 * 64 * 4);
  bf16* comb = (bf16*)alloc(4096l * 512 * 2);
  bf16* zb = (bf16*)alloc(4096l * 512 * 2);
  bf16* wcombb = (bf16*)alloc(512l * 512 * 2);
  bf16* woutb = (bf16*)alloc(512l * 512 * 2);
  float* kpart = (float*)alloc(16l * 2048 * 64 * 4);  // split-K f32 partials (16 chunks)

  // ---- transpose to f16 planes + conv-weight plane cast + RoPE table ----
  k_transpose16<<<dim3(128, 17), dim3(32, 8), 0, stream>>>(x, xth, xtl, w_in, winh, winl, ropet);
  // ---- conv (f16x2) + all remaining weight prep in one dispatch ----
  k_conv_prep<<<dim3(64, 24), 256, 0, stream>>>(xth, xtl, winh, winl, xsf, b_in, wq, wk, wv, w_strat,
                                                b_strat, kc_w1, kc_w2, vc_w1, vc_w2, w_comb, w_out,
                                                wqkh, wqkl, wvs, bias2, kw1h, kw1l, kw2h, kw2l,
                                                vw1b, vw2b, wcombb, woutb);
  k_rmsnorm<<<4096, 256, 0, stream>>>(xsf, g_norm, hhi, hlo, hbf);
  // ---- qk f16x2 GEMM with fused repack epilogue (+ T2 bf16 GEMM w/ fused
  //      v-repack: vvb/vinb written straight from the T2 accumulator) ----
  k_fused_qk_t2<<<dim3(64, 25, 1), 256, 0, stream>>>(hhi, hlo, wqkh, wqkl, qhh, qhl, kinh, kinl, rq, rk,
                                                     k_pos, ropet, hbf, wvs, T2, bias2, v_pos, vvb, vinb);
  k_fused_mlp1<<<dim3(32, 32, 1), 256, 0, stream>>>(kinh, kinl, kw1h, kw1l, hidh, hidl, kc_b1, vinb, vw1b,
                                                    hidv, vc_b1);
  k_fused_mlp2<<<dim3(32, 17, 1), 256, 0, stream>>>(hidh, hidl, kw2h, kw2l, kpart, hidv, vw2b, cvc, vc_b2);
  k_repackB<<<640, 256, 0, stream>>>(kpart, cvc, mem_k, mem_v, kc_b2, ckbh, ckbl, cvtb);
  // ---- FUSED csim+softmax+topk ----
  k_selsm<<<dim3(256, 8), 256, 0, stream>>>(qhh, qhl, ckbh, ckbl, pb, selb);
  gemm_bt<EPI_F32><<<dim3(64, 1, 8), 256, 0, stream>>>(pb, cvtb, co, 288, 64, 4096l * 288, 64l * 288,
                                                       4096l * 64, nullptr, nullptr);
  k_fineslide<<<8192, 256, 0, stream>>>(rq, rk, vvb, co, selb, T2, comb);
  // ---- output mixing ----
  gemm_bt<EPI_BF16><<<dim3(64, 8, 1), 256, 0, stream>>>(comb, wcombb, zb, 512, 512, 0, 0, 0, nullptr, nullptr);
  gemm_bt<EPI_FINAL><<<dim3(8, 64, 1), 256, 0, stream>>>(woutb, zb, d_out, 512, 4096, 0, 0, 0, b_out, xsf);
}